// Round 6
// baseline (486.977 us; speedup 1.0000x reference)
//
#include <hip/hip_runtime.h>

// GRU: H=32, I=1, B=2048, T=1024, fused output Linear(32,1).
// v6: LDS-pipe decongestion. v5 was DS-bound (~100 DS-cyc/wave-step x 8
// waves/CU == the 350 us wall). h broadcast now goes through v_readlane ->
// SGPR pairs (VALU, not DS); v_pk_fma_f32 takes the SGPR pair as src1.
// Gate-split across wave halves: chainA = r (half0 lanes) / z (half1 lanes)
// via per-lane weights, chainB = n (both halves); one ds_bpermute + 2
// cndmask gives all lanes correct (r,z,n) -> identical h in both halves.
// DS ops/step: 13 -> 2 (1 bperm + 1 y-stash write).

constexpr int H  = 32;
constexpr int TT = 1024;
constexpr int BB = 2048;

typedef float v2f __attribute__((ext_vector_type(2)));

__device__ __forceinline__ float rcp_(float a)  { return __builtin_amdgcn_rcpf(a); }
__device__ __forceinline__ float exp2_(float a) { return __builtin_amdgcn_exp2f(a); }
__device__ __forceinline__ float bperm_(int bp, float v) {
    return __uint_as_float((unsigned)__builtin_amdgcn_ds_bpermute(bp, (int)__float_as_uint(v)));
}
__device__ __forceinline__ float rdlane_(float v, int l) {
    return __uint_as_float((unsigned)__builtin_amdgcn_readlane((int)__float_as_uint(v), l));
}

// packed fp32 ops with SGPR-pair broadcast operand (1 scalar src: legal VOP3P)
#define PKS_MUL(d, a, b) asm("v_pk_mul_f32 %0, %1, %2" : "=v"(d) : "v"(a), "s"(b))
#define PKS_FMA(d, a, b) asm("v_pk_fma_f32 %0, %1, %2, %0" : "+v"(d) : "v"(a), "s"(b))

__global__ __launch_bounds__(256, 2)
__attribute__((amdgpu_waves_per_eu(2, 2)))
void gru_fused(const float* __restrict__ x,      // [B,T]
               const float* __restrict__ h0,     // [1,B,H]
               const float* __restrict__ W_ih,   // [3H,1]
               const float* __restrict__ W_hh,   // [3H,H]
               const float* __restrict__ b_ih,   // [3H]
               const float* __restrict__ b_hh,   // [3H]
               const float* __restrict__ W_out,  // [1,H]
               const float* __restrict__ b_out,  // [1]
               float* __restrict__ out)          // y[B,T] ++ h_n[B,H]
{
    __shared__ float ybuf[4][33 * 32];           // y transpose, 33-stride

    const int tid  = threadIdx.x;
    const int w    = tid >> 6;
    const int lane = tid & 63;
    const int half = lane >> 5;
    const int j    = lane & 31;
    const int b    = (blockIdx.x << 2) | w;

    const float NL2E = -1.44269504f;   // -log2(e) folded into r,z path
    const float P2L2 =  2.88539008f;   //  2*log2(e) folded into n path

    // chainA weights: half0 -> r-row j, half1 -> z-row j (both *NL2E)
    // chainB weights: n-row j (both halves, *P2L2)
    const float* WAp = &W_hh[((half ? H : 0) + j) * H];
    const float* WBp = &W_hh[(2 * H + j) * H];
    v2f WA[16], WB[16];
#pragma unroll
    for (int k = 0; k < 16; ++k) {
        WA[k] = ((const v2f*)WAp)[k] * NL2E;
        WB[k] = ((const v2f*)WBp)[k] * P2L2;
    }
    const float bA  = (half ? (b_ih[H + j] + b_hh[H + j])
                            : (b_ih[j]     + b_hh[j]    )) * NL2E;
    const float wiA = (half ? W_ih[H + j] : W_ih[j]) * NL2E;
    const float bhn = b_hh[2 * H + j] * P2L2;
    const float win = W_ih[2 * H + j] * P2L2;
    const float bin = b_ih[2 * H + j] * P2L2;
    const float wo  = W_out[j];
    const float bo  = b_out[0];

    float h = h0[b * H + j];            // lane (either half) holds h_j

    const float* xb = x + (size_t)b * TT;
    float*       yb = out + (size_t)b * TT;
    float* yrow = &ybuf[w][0];

    const int bp = (lane ^ 32) << 2;    // ds_bpermute byte addr (xor-32 swap)

    float xv = xb[j];                   // first 32-timestep chunk

#pragma unroll 1
    for (int t0 = 0; t0 < TT; t0 += 32) {
        const int tn = (t0 + 32) & (TT - 1);
        const float xv_next = xb[tn + j];    // prefetch next chunk (wraps: harmless)

#pragma unroll 1
        for (int s0 = 0; s0 < 32; s0 += 8) {
#pragma unroll
            for (int u = 0; u < 8; ++u) {
                const int s = s0 + u;

                // broadcast h_0..h_31 into 16 SGPR pairs (no LDS!)
                v2f hp[16];
#pragma unroll
                for (int k = 0; k < 16; ++k) {
                    v2f t;
                    t.x = rdlane_(h, 2 * k);
                    t.y = rdlane_(h, 2 * k + 1);
                    hp[k] = t;
                }
                const float xt = rdlane_(xv, s);

                // 2 packed chains x 2 sub-chains (ILP): 32 pk ops total
                v2f aA0, aA1, aB0, aB1;
                PKS_MUL(aA0, WA[0], hp[0]);  PKS_MUL(aB0, WB[0], hp[0]);
                PKS_MUL(aA1, WA[8], hp[8]);  PKS_MUL(aB1, WB[8], hp[8]);
#pragma unroll
                for (int k = 1; k < 8; ++k) {
                    PKS_FMA(aA0, WA[k],     hp[k]);
                    PKS_FMA(aB0, WB[k],     hp[k]);
                    PKS_FMA(aA1, WA[8 + k], hp[8 + k]);
                    PKS_FMA(aB1, WB[8 + k], hp[8 + k]);
                }

                float accA = (aA0.x + aA0.y) + (aA1.x + aA1.y) + bA;
                accA = __builtin_fmaf(xt, wiA, accA);        // half0: r-pre, half1: z-pre
                const float accn = (aB0.x + aB0.y) + (aB1.x + aB1.y) + bhn;

                // exchange chainA across halves; select per half
                const float acx  = bperm_(bp, accA);
                const float accr = half ? acx  : accA;
                const float accz = half ? accA : acx;

                const float r = rcp_(1.0f + exp2_(accr));
                const float z = rcp_(1.0f + exp2_(accz));
                const float npre = __builtin_fmaf(r, accn, __builtin_fmaf(xt, win, bin));
                const float n = __builtin_fmaf(-2.0f, rcp_(1.0f + exp2_(npre)), 1.0f);

                h = __builtin_fmaf(z, h - n, n);             // identical in both halves

                yrow[33 * s + j] = wo * h;   // both halves: same value, same addr (benign)
            }
        }

        // amortized y reduction: lane (half,j) sums row j; 33-stride conflict-free
        __builtin_amdgcn_wave_barrier();
        float s0a = 0.0f, s1a = 0.0f, s2a = 0.0f, s3a = 0.0f;
#pragma unroll
        for (int k = 0; k < 32; k += 4) {
            s0a += yrow[33 * j + k + 0];
            s1a += yrow[33 * j + k + 1];
            s2a += yrow[33 * j + k + 2];
            s3a += yrow[33 * j + k + 3];
        }
        if (half == 0) {
            yb[t0 + j] = (s0a + s1a) + (s2a + s3a) + bo;
        }
        __builtin_amdgcn_wave_barrier();   // next chunk's writes must not pass reads

        xv = xv_next;
    }

    if (half == 0) {
        out[(size_t)BB * TT + b * H + j] = h;   // h_n
    }
}

extern "C" void kernel_launch(void* const* d_in, const int* in_sizes, int n_in,
                              void* d_out, int out_size, void* d_ws, size_t ws_size,
                              hipStream_t stream) {
    const float* x     = (const float*)d_in[0];
    const float* h0    = (const float*)d_in[1];
    const float* W_ih  = (const float*)d_in[2];
    const float* W_hh  = (const float*)d_in[3];
    const float* b_ih  = (const float*)d_in[4];
    const float* b_hh  = (const float*)d_in[5];
    const float* W_out = (const float*)d_in[6];
    const float* b_out = (const float*)d_in[7];
    float* out = (float*)d_out;

    dim3 grid(BB / 4);   // 512 blocks, 4 waves (batches) each
    dim3 block(256);
    gru_fused<<<grid, block, 0, stream>>>(x, h0, W_ih, W_hh, b_ih, b_hh,
                                          W_out, b_out, out);
}

// Round 7
// 340.971 us; speedup vs baseline: 1.4282x; 1.4282x over previous
//
#include <hip/hip_runtime.h>

// GRU: H=32, I=1, B=2048, T=1024, fused output Linear(32,1).
// Mapping: 1 batch per 64-lane wave (2048 waves = 2/SIMD). Lane (half, j)
// owns gate rows {r,z,n} of unit j for K-range [16*half, 16*half+16).
// v7: LDS traffic halved via f16. v5 was LDS-pipe-bound (13 DS instrs ~= 94
// DS-cyc/batch-step x 8 streams/CU == the 342 us wall; v5's VALU cut didn't
// move the wall). h is published as f16 (ds_write_b16) and each lane reads
// its K-half as 2x ds_read_b128 (was 8x b64); MACs via v_dot2_f32_f16
// (f16 pairs, fp32 accumulate). DS instrs/step: 13 -> 8. y path and the
// 3-bperm K-half combine stay exactly v5 (known correct).

constexpr int H  = 32;
constexpr int TT = 1024;
constexpr int BB = 2048;

typedef _Float16 hf2 __attribute__((ext_vector_type(2)));
typedef _Float16 hf8 __attribute__((ext_vector_type(8)));

__device__ __forceinline__ float rcp_(float a)  { return __builtin_amdgcn_rcpf(a); }
__device__ __forceinline__ float exp2_(float a) { return __builtin_amdgcn_exp2f(a); }
__device__ __forceinline__ float bperm_(int bp, float v) {
    return __uint_as_float((unsigned)__builtin_amdgcn_ds_bpermute(bp, (int)__float_as_uint(v)));
}
__device__ __forceinline__ float rdlane_(float v, int l) {
    return __uint_as_float((unsigned)__builtin_amdgcn_readlane((int)__float_as_uint(v), l));
}
__device__ __forceinline__ float dot2_(hf2 a, hf2 b, float c) {
    return __builtin_amdgcn_fdot2(a, b, c, false);
}

__global__ __launch_bounds__(256, 2)
void gru_fused(const float* __restrict__ x,      // [B,T]
               const float* __restrict__ h0,     // [1,B,H]
               const float* __restrict__ W_ih,   // [3H,1]
               const float* __restrict__ W_hh,   // [3H,H]
               const float* __restrict__ b_ih,   // [3H]
               const float* __restrict__ b_hh,   // [3H]
               const float* __restrict__ W_out,  // [1,H]
               const float* __restrict__ b_out,  // [1]
               float* __restrict__ out)          // y[B,T] ++ h_n[B,H]
{
    __shared__ __align__(16) _Float16 hbuf[4][32];   // [wave][h as f16]
    __shared__ float ybuf[4][33 * 32];               // y transpose, 33-stride

    const int tid  = threadIdx.x;
    const int w    = tid >> 6;
    const int lane = tid & 63;
    const int half = lane >> 5;
    const int j    = lane & 31;
    const int b    = (blockIdx.x << 2) | w;

    const float NL2E = -1.44269504f;   // -log2(e): folded into r,z weights
    const float P2L2 =  2.88539008f;   //  2*log2(e): folded into n weights

    // --- weights: own K-half of rows {j, H+j, 2H+j}, pre-scaled, f16 pairs ---
    const float* Wrp = &W_hh[(0 * H + j) * H + 16 * half];
    const float* Wzp = &W_hh[(1 * H + j) * H + 16 * half];
    const float* Wnp = &W_hh[(2 * H + j) * H + 16 * half];
    hf2 Wr[8], Wz[8], Wn[8];
#pragma unroll
    for (int k = 0; k < 8; ++k) {
        hf2 a, c, d;
        a.x = (_Float16)(Wrp[2 * k] * NL2E); a.y = (_Float16)(Wrp[2 * k + 1] * NL2E);
        c.x = (_Float16)(Wzp[2 * k] * NL2E); c.y = (_Float16)(Wzp[2 * k + 1] * NL2E);
        d.x = (_Float16)(Wnp[2 * k] * P2L2); d.y = (_Float16)(Wnp[2 * k + 1] * P2L2);
        Wr[k] = a; Wz[k] = c; Wn[k] = d;
    }
    // bias / input-weight terms enter accumulators once (zero on half1)
    const float wir = half ? 0.0f : (W_ih[j] * NL2E);
    const float wiz = half ? 0.0f : (W_ih[H + j] * NL2E);
    const float br  = half ? 0.0f : ((b_ih[j] + b_hh[j]) * NL2E);
    const float bz  = half ? 0.0f : ((b_ih[H + j] + b_hh[H + j]) * NL2E);
    const float bhn = half ? 0.0f : (b_hh[2 * H + j] * P2L2);
    const float win = W_ih[2 * H + j] * P2L2;
    const float bin = b_ih[2 * H + j] * P2L2;
    const float wo  = W_out[j];
    const float bo  = b_out[0];

    float h = h0[b * H + j];

    const float* xb = x + (size_t)b * TT;
    float*       yb = out + (size_t)b * TT;

    _Float16* hw = &hbuf[w][0];
    // own K-half as two 16B vectors (h_{16h}..h_{16h+15}); 32B offset keeps
    // 16B alignment; the two halves' addresses are same-address broadcasts
    // within each half -> conflict-free.
    const hf8* hv = (const hf8*)&hbuf[w][16 * half];
    float* yw   = &ybuf[w][j];
    float* yrow = &ybuf[w][0];

    const int bp = (lane ^ 32) << 2;   // ds_bpermute byte addr (xor-32 swap)

#pragma unroll 1
    for (int t0 = 0; t0 < TT; t0 += 32) {
        const float xv = xb[t0 + j];   // lane j holds x[t0+j]

#pragma unroll
        for (int s = 0; s < 32; ++s) {
            hw[j] = (_Float16)h;       // both halves: same addr, same value
            __builtin_amdgcn_wave_barrier();
            const hf8 A = hv[0];       // h pairs 0..3 of own K-half
            const hf8 B = hv[1];       // h pairs 4..7
            const hf2 q0 = __builtin_shufflevector(A, A, 0, 1);
            const hf2 q1 = __builtin_shufflevector(A, A, 2, 3);
            const hf2 q2 = __builtin_shufflevector(A, A, 4, 5);
            const hf2 q3 = __builtin_shufflevector(A, A, 6, 7);
            const hf2 q4 = __builtin_shufflevector(B, B, 0, 1);
            const hf2 q5 = __builtin_shufflevector(B, B, 2, 3);
            const hf2 q6 = __builtin_shufflevector(B, B, 4, 5);
            const hf2 q7 = __builtin_shufflevector(B, B, 6, 7);

            const float xt = rdlane_(xv, s);

            float accr = br, accz = bz, accn = bhn;
            accr = dot2_(Wr[0], q0, accr); accz = dot2_(Wz[0], q0, accz); accn = dot2_(Wn[0], q0, accn);
            accr = dot2_(Wr[1], q1, accr); accz = dot2_(Wz[1], q1, accz); accn = dot2_(Wn[1], q1, accn);
            accr = dot2_(Wr[2], q2, accr); accz = dot2_(Wz[2], q2, accz); accn = dot2_(Wn[2], q2, accn);
            accr = dot2_(Wr[3], q3, accr); accz = dot2_(Wz[3], q3, accz); accn = dot2_(Wn[3], q3, accn);
            accr = dot2_(Wr[4], q4, accr); accz = dot2_(Wz[4], q4, accz); accn = dot2_(Wn[4], q4, accn);
            accr = dot2_(Wr[5], q5, accr); accz = dot2_(Wz[5], q5, accz); accn = dot2_(Wn[5], q5, accn);
            accr = dot2_(Wr[6], q6, accr); accz = dot2_(Wz[6], q6, accz); accn = dot2_(Wn[6], q6, accn);
            accr = dot2_(Wr[7], q7, accr); accz = dot2_(Wz[7], q7, accz); accn = dot2_(Wn[7], q7, accn);

            accr = __builtin_fmaf(xt, wir, accr);
            accz = __builtin_fmaf(xt, wiz, accz);

            // combine the two K-halves (xor-32 swap + add)
            accr += bperm_(bp, accr);
            accz += bperm_(bp, accz);
            accn += bperm_(bp, accn);

            // gates: scales pre-folded; sigmoid = rcp(1+exp2(acc'))
            const float r = rcp_(1.0f + exp2_(accr));
            const float z = rcp_(1.0f + exp2_(accz));
            const float npre = __builtin_fmaf(r, accn, __builtin_fmaf(xt, win, bin));
            const float n = __builtin_fmaf(-2.0f, rcp_(1.0f + exp2_(npre)), 1.0f);

            h = __builtin_fmaf(z, h - n, n);   // (1-z)*n + z*h

            yw[33 * s] = wo * h;               // both halves: same addr/value (benign)
        }

        // amortized y reduction: lane (half,j) sums row j (broadcast across halves)
        __builtin_amdgcn_wave_barrier();
        float s0 = 0.0f, s1 = 0.0f, s2 = 0.0f, s3 = 0.0f;
#pragma unroll
        for (int k = 0; k < 32; k += 4) {
            s0 += yrow[33 * j + k + 0];
            s1 += yrow[33 * j + k + 1];
            s2 += yrow[33 * j + k + 2];
            s3 += yrow[33 * j + k + 3];
        }
        if (half == 0) {
            yb[t0 + j] = (s0 + s1) + (s2 + s3) + bo;
        }
        __builtin_amdgcn_wave_barrier();   // next chunk's writes must not pass reads
    }

    if (half == 0) {
        out[(size_t)BB * TT + b * H + j] = h;   // h_n
    }
}

extern "C" void kernel_launch(void* const* d_in, const int* in_sizes, int n_in,
                              void* d_out, int out_size, void* d_ws, size_t ws_size,
                              hipStream_t stream) {
    const float* x     = (const float*)d_in[0];
    const float* h0    = (const float*)d_in[1];
    const float* W_ih  = (const float*)d_in[2];
    const float* W_hh  = (const float*)d_in[3];
    const float* b_ih  = (const float*)d_in[4];
    const float* b_hh  = (const float*)d_in[5];
    const float* W_out = (const float*)d_in[6];
    const float* b_out = (const float*)d_in[7];
    float* out = (float*)d_out;

    dim3 grid(BB / 4);   // 512 blocks, 4 waves (batches) each
    dim3 block(256);
    gru_fused<<<grid, block, 0, stream>>>(x, h0, W_ih, W_hh, b_ih, b_hh,
                                          W_out, b_out, out);
}